// Round 5
// baseline (430.166 us; speedup 1.0000x reference)
//
#include <hip/hip_runtime.h>
#include <hip/hip_bf16.h>
#include <math.h>

#define SEQ 512
#define DM  256
#define NH  8

typedef __attribute__((ext_vector_type(4))) float  f32x4;
typedef __attribute__((ext_vector_type(8))) __bf16 bf16x8;
typedef __attribute__((ext_vector_type(8))) short  s16x8;

// native cast -> v_cvt_pk_bf16_f32 (RNE), same numerics as manual RNE
__device__ __forceinline__ short fb(float x) {
  __bf16 h = (__bf16)x;
  return __builtin_bit_cast(short, h);
}
__device__ __forceinline__ unsigned short f2bf(float f) {
  unsigned int u = __builtin_bit_cast(unsigned int, f);
  u += 0x7fffu + ((u >> 16) & 1u);
  return (unsigned short)(u >> 16);
}
__device__ __forceinline__ float bf2f(unsigned short h) {
  unsigned int u = ((unsigned int)h) << 16;
  return __builtin_bit_cast(float, u);
}
__device__ __forceinline__ s16x8 cvt8(float4 a, float4 b) {
  s16x8 o;
  o[0]=fb(a.x); o[1]=fb(a.y); o[2]=fb(a.z); o[3]=fb(a.w);
  o[4]=fb(b.x); o[5]=fb(b.y); o[6]=fb(b.z); o[7]=fb(b.w);
  return o;
}

// ---------------------------------------------------------------------------
// K0: blocks 0..31 convert k (f32->bf16); blocks 32..63 transpose v -> vT bf16
__global__ __launch_bounds__(256) void k0_convert(const float* __restrict__ kin,
                                                  const float* __restrict__ vin,
                                                  unsigned short* __restrict__ kbf,
                                                  unsigned short* __restrict__ vT) {
  __shared__ unsigned short tl[64][72];
  int b = blockIdx.x, t = threadIdx.x;
  if (b < 32) {
    int base = b * 4096 + t * 16;
    float4 a0 = *(const float4*)(kin + base);
    float4 a1 = *(const float4*)(kin + base + 4);
    float4 a2 = *(const float4*)(kin + base + 8);
    float4 a3 = *(const float4*)(kin + base + 12);
    *(s16x8*)(kbf + base)     = cvt8(a0, a1);
    *(s16x8*)(kbf + base + 8) = cvt8(a2, a3);
  } else {
    int tb = b - 32;
    int i0 = (tb >> 2) * 64;
    int m0 = (tb & 3) * 64;
    int r = t >> 2, cq = t & 3;
    #pragma unroll
    for (int u = 0; u < 4; u++) {
      float4 x = *(const float4*)(vin + (size_t)(i0 + r) * DM + m0 + cq * 16 + u * 4);
      tl[cq*16 + u*4 + 0][r] = (unsigned short)fb(x.x);
      tl[cq*16 + u*4 + 1][r] = (unsigned short)fb(x.y);
      tl[cq*16 + u*4 + 2][r] = (unsigned short)fb(x.z);
      tl[cq*16 + u*4 + 3][r] = (unsigned short)fb(x.w);
    }
    __syncthreads();
    int mm = t >> 2;
    s16x8 w0, w1;
    #pragma unroll
    for (int e = 0; e < 8; e++) { w0[e] = tl[mm][cq*16 + e]; w1[e] = tl[mm][cq*16 + 8 + e]; }
    *(s16x8*)(vT + (size_t)(m0 + mm) * SEQ + i0 + cq * 16)     = w0;
    *(s16x8*)(vT + (size_t)(m0 + mm) * SEQ + i0 + cq * 16 + 8) = w1;
  }
}

// ---------------------------------------------------------------------------
// K1: qp = q @ Wq^T  (f32 out)
__global__ __launch_bounds__(256) void k1_qproj(const float* __restrict__ q,
                                                const float* __restrict__ Wq,
                                                float* __restrict__ qpf) {
  __shared__ __align__(16) float qrow[DM];
  int i = blockIdx.x, t = threadIdx.x;
  if (t < 64) *(float4*)&qrow[t*4] = *(const float4*)(q + (size_t)i * DM + t * 4);
  __syncthreads();
  int w = t >> 6, lane = t & 63;
  for (int jj = 0; jj < 64; jj++) {
    int j = w * 64 + jj;
    float4 wv = *(const float4*)(Wq + (size_t)j * DM + lane * 4);
    float s = wv.x*qrow[lane*4] + wv.y*qrow[lane*4+1] + wv.z*qrow[lane*4+2] + wv.w*qrow[lane*4+3];
    #pragma unroll
    for (int off = 32; off; off >>= 1) s += __shfl_xor(s, off);
    if (lane == 0) qpf[(size_t)i*DM + j] = s;
  }
}

// ---------------------------------------------------------------------------
// ka3: for 4 j's: T_j = qp[m0:+64] @ Wk_j^T (N=256,K=256,BK=64), then
// acc[i,k] += qp_f32[i,j]*T_j[i,k]; one atomicAdd pass into af.
// grid 512 = head(8,XCD) x jsplit(8) x itile(8).  256 thr, ~48 KiB LDS.
__global__ __launch_bounds__(256) void ka3(const float* __restrict__ Wk,
                                           const float* __restrict__ qpf,
                                           float* __restrict__ af) {
  __shared__ __align__(16) unsigned short lA[64 * 76];
  __shared__ __align__(16) unsigned short lB[256 * 76];
  __shared__ __align__(16) float lqs[64 * 4];
  int bid = blockIdx.x;
  int lid = (bid & 7) * 64 + (bid >> 3);           // bijective, head == bid&7
  int head = lid >> 6, jsplit = (lid >> 3) & 7, itile = lid & 7;
  int m0 = itile * 64;
  int t = threadIdx.x, wc = t >> 6, lane = t & 63;
  int r = lane & 15, hi = lane >> 4;

  { int row = t >> 2, jl = t & 3;                  // stage lqs once
    lqs[row*4 + jl] = qpf[(size_t)(m0+row)*DM + head*32 + jsplit*4 + jl]; }

  f32x4 acc[4][4] = {};
  int srow = t >> 2, sc16 = (t & 3) * 16;          // staging decomposition

  for (int jj = 0; jj < 4; jj++) {
    int jcol = head*32 + jsplit*4 + jj;
    const float* Bbase = Wk + (size_t)jcol * 65536;
    f32x4 tmp[4][4] = {};
    for (int kt = 0; kt < 4; kt++) {
      __syncthreads();                             // prev reads done
      { // stage lA: 64 x 64 (qp f32->bf16)
        const float* src = qpf + (size_t)(m0+srow)*DM + kt*64 + sc16;
        float4 x0 = *(const float4*)src,     x1 = *(const float4*)(src+4);
        float4 x2 = *(const float4*)(src+8), x3 = *(const float4*)(src+12);
        *(s16x8*)&lA[srow*76 + sc16]     = cvt8(x0, x1);
        *(s16x8*)&lA[srow*76 + sc16 + 8] = cvt8(x2, x3);
      }
      #pragma unroll
      for (int p = 0; p < 4; p++) {                // stage lB: 256 x 64
        int row = p*64 + srow;
        const float* src = Bbase + (size_t)row*256 + kt*64 + sc16;
        float4 x0 = *(const float4*)src,     x1 = *(const float4*)(src+4);
        float4 x2 = *(const float4*)(src+8), x3 = *(const float4*)(src+12);
        *(s16x8*)&lB[row*76 + sc16]     = cvt8(x0, x1);
        *(s16x8*)&lB[row*76 + sc16 + 8] = cvt8(x2, x3);
      }
      __syncthreads();
      #pragma unroll
      for (int kk = 0; kk < 2; kk++) {
        int kc = kk*32 + hi*8;
        bf16x8 afr[4], bfr[4];
        #pragma unroll
        for (int mf = 0; mf < 4; mf++) afr[mf] = *(const bf16x8*)&lA[(mf*16 + r)*76 + kc];
        #pragma unroll
        for (int nf = 0; nf < 4; nf++) bfr[nf] = *(const bf16x8*)&lB[(wc*64 + nf*16 + r)*76 + kc];
        #pragma unroll
        for (int mf = 0; mf < 4; mf++)
          #pragma unroll
          for (int nf = 0; nf < 4; nf++)
            tmp[mf][nf] = __builtin_amdgcn_mfma_f32_16x16x32_bf16(afr[mf], bfr[nf], tmp[mf][nf], 0, 0, 0);
      }
    }
    #pragma unroll
    for (int mf = 0; mf < 4; mf++)
      #pragma unroll
      for (int qq = 0; qq < 4; qq++) {
        float sv = lqs[(mf*16 + hi*4 + qq)*4 + jj];
        #pragma unroll
        for (int nf = 0; nf < 4; nf++) acc[mf][nf][qq] += sv * tmp[mf][nf][qq];
      }
  }
  #pragma unroll
  for (int mf = 0; mf < 4; mf++)
    #pragma unroll
    for (int nf = 0; nf < 4; nf++)
      #pragma unroll
      for (int qq = 0; qq < 4; qq++) {
        int row = m0 + mf*16 + hi*4 + qq;
        int col = wc*64 + nf*16 + r;
        atomicAdd(&af[((size_t)head * SEQ + row) * DM + col], acc[mf][nf][qq]);
      }
}

// ---------------------------------------------------------------------------
// ko3: for 4 j's: U_j = qp[m0:+32] @ Wv_j^T (N=256,K=256,BK=64), then
// out[i,j] += sum_b w[head,i,b]*U_j[i,b] (shfl-reduce over 16 lanes + atomic).
// grid 1024 = head(8,XCD) x jsplit(8) x itile(16).  256 thr, ~59 KiB LDS.
__global__ __launch_bounds__(256) void ko3(const float* __restrict__ Wv,
                                           const float* __restrict__ qpf,
                                           const unsigned short* __restrict__ wbf,
                                           float* __restrict__ out) {
  __shared__ __align__(16) unsigned short lA[32 * 76];
  __shared__ __align__(16) unsigned short lB[256 * 76];
  __shared__ __align__(16) unsigned short lw[32 * 264];
  int bid = blockIdx.x;
  int lid = (bid & 7) * 128 + (bid >> 3);          // bijective, head == bid&7
  int head = lid >> 7, jsplit = (lid >> 4) & 7, itile = lid & 15;
  int m0 = itile * 32;
  int t = threadIdx.x, wc = t >> 6, lane = t & 63;
  int r = lane & 15, hi = lane >> 4;

  { // stage lw once: w[head, m0..+32, :] bf16 copy
    int row = t >> 3, c32 = (t & 7) * 32;
    const unsigned short* sw = wbf + ((size_t)head * SEQ + m0 + row) * DM + c32;
    #pragma unroll
    for (int u = 0; u < 4; u++)
      *(s16x8*)&lw[row*264 + c32 + u*8] = *(const s16x8*)(sw + u*8);
  }

  int srow = t >> 2, sc16 = (t & 3) * 16;
  int arow = t >> 3, ac8 = (t & 7) * 8;

  for (int jj = 0; jj < 4; jj++) {
    int jcol = head*32 + jsplit*4 + jj;
    const float* Bbase = Wv + (size_t)jcol * 65536;
    f32x4 tmp[2][4] = {};
    for (int kt = 0; kt < 4; kt++) {
      __syncthreads();
      { // stage lA: 32 x 64 (qp f32->bf16), 8 f32/thread
        const float* src = qpf + (size_t)(m0+arow)*DM + kt*64 + ac8;
        float4 x0 = *(const float4*)src, x1 = *(const float4*)(src+4);
        *(s16x8*)&lA[arow*76 + ac8] = cvt8(x0, x1);
      }
      #pragma unroll
      for (int p = 0; p < 4; p++) {                // stage lB: 256 x 64
        int row = p*64 + srow;
        const float* src = Bbase + (size_t)row*256 + kt*64 + sc16;
        float4 x0 = *(const float4*)src,     x1 = *(const float4*)(src+4);
        float4 x2 = *(const float4*)(src+8), x3 = *(const float4*)(src+12);
        *(s16x8*)&lB[row*76 + sc16]     = cvt8(x0, x1);
        *(s16x8*)&lB[row*76 + sc16 + 8] = cvt8(x2, x3);
      }
      __syncthreads();
      #pragma unroll
      for (int kk = 0; kk < 2; kk++) {
        int kc = kk*32 + hi*8;
        bf16x8 afr[2], bfr[4];
        #pragma unroll
        for (int mf = 0; mf < 2; mf++) afr[mf] = *(const bf16x8*)&lA[(mf*16 + r)*76 + kc];
        #pragma unroll
        for (int nf = 0; nf < 4; nf++) bfr[nf] = *(const bf16x8*)&lB[(wc*64 + nf*16 + r)*76 + kc];
        #pragma unroll
        for (int mf = 0; mf < 2; mf++)
          #pragma unroll
          for (int nf = 0; nf < 4; nf++)
            tmp[mf][nf] = __builtin_amdgcn_mfma_f32_16x16x32_bf16(afr[mf], bfr[nf], tmp[mf][nf], 0, 0, 0);
      }
    }
    // epilogue: out[i, jcol] += sum_b tmp * w   (b-cols: wc*64 + nf*16 + r)
    #pragma unroll
    for (int mf = 0; mf < 2; mf++)
      #pragma unroll
      for (int qq = 0; qq < 4; qq++) {
        int rloc = mf*16 + hi*4 + qq;
        float pp = 0.f;
        #pragma unroll
        for (int nf = 0; nf < 4; nf++)
          pp += tmp[mf][nf][qq] * bf2f(lw[rloc*264 + wc*64 + nf*16 + r]);
        pp += __shfl_xor(pp, 1);
        pp += __shfl_xor(pp, 2);
        pp += __shfl_xor(pp, 4);
        pp += __shfl_xor(pp, 8);
        if (r == 0) atomicAdd(&out[(size_t)(m0 + rloc) * DM + jcol], pp);
      }
  }
}

// ---------------------------------------------------------------------------
// Small 64x64-tile NT GEMM: C[M,N] = A[M,K] * B[N,K]^T, 4 waves (2x2), bf16 MFMA
template<int CONVA, int OUTBF>
__global__ __launch_bounds__(256) void gemm_small(const void* __restrict__ Ap,
                                                  const unsigned short* __restrict__ B,
                                                  void* __restrict__ Cp,
                                                  int M, int N, int K, int nMtiles) {
  __shared__ __align__(16) unsigned short lA[64 * 72];
  __shared__ __align__(16) unsigned short lB[64 * 72];
  int bid = blockIdx.x;
  int mtile = bid % nMtiles, ntile = bid / nMtiles;
  int m0 = mtile * 64, n0 = ntile * 64;
  int t = threadIdx.x, w = t >> 6, lane = t & 63;
  int wr = w >> 1, wcc = w & 1;
  f32x4 acc[2][2] = {};
  for (int kt = 0; kt < K; kt += 64) {
    __syncthreads();
    #pragma unroll
    for (int rep = 0; rep < 2; rep++) {
      int sc = rep * 256 + t;
      int row = sc >> 3, c8 = sc & 7;
      if (CONVA) {
        const float* src = (const float*)Ap + (size_t)(m0 + row) * K + kt + c8 * 8;
        float4 u0 = *(const float4*)src, u1 = *(const float4*)(src + 4);
        *(s16x8*)&lA[row * 72 + c8 * 8] = cvt8(u0, u1);
      } else {
        *(s16x8*)&lA[row * 72 + c8 * 8] =
            *(const s16x8*)((const unsigned short*)Ap + (size_t)(m0 + row) * K + kt + c8 * 8);
      }
      *(s16x8*)&lB[row * 72 + c8 * 8] = *(const s16x8*)(B + (size_t)(n0 + row) * K + kt + c8 * 8);
    }
    __syncthreads();
    #pragma unroll
    for (int kk = 0; kk < 2; kk++) {
      int r = lane & 15, kc = kk * 32 + (lane >> 4) * 8;
      bf16x8 afr[2], bfr[2];
      #pragma unroll
      for (int mf = 0; mf < 2; mf++) afr[mf] = *(const bf16x8*)&lA[(wr*32 + mf*16 + r) * 72 + kc];
      #pragma unroll
      for (int nf = 0; nf < 2; nf++) bfr[nf] = *(const bf16x8*)&lB[(wcc*32 + nf*16 + r) * 72 + kc];
      #pragma unroll
      for (int mf = 0; mf < 2; mf++)
        #pragma unroll
        for (int nf = 0; nf < 2; nf++)
          acc[mf][nf] = __builtin_amdgcn_mfma_f32_16x16x32_bf16(afr[mf], bfr[nf], acc[mf][nf], 0, 0, 0);
    }
  }
  int cr = (lane >> 4) * 4, cc = lane & 15;
  #pragma unroll
  for (int mf = 0; mf < 2; mf++)
    #pragma unroll
    for (int nf = 0; nf < 2; nf++)
      #pragma unroll
      for (int qq = 0; qq < 4; qq++) {
        int row = m0 + wr*32 + mf*16 + cr + qq;
        int col = n0 + wcc*32 + nf*16 + cc;
        float vv = acc[mf][nf][qq];
        if (OUTBF) ((unsigned short*)Cp)[(size_t)row * N + col] = f2bf(vv);
        else       ((float*)Cp)[(size_t)row * N + col] = vv;
      }
}

// ---------------------------------------------------------------------------
// softmax over rows of logits[n*512+i][l], causal l<=i, scale 1/sqrt(512)
__global__ __launch_bounds__(256) void k4b_softmax(const float* __restrict__ logits,
                                                   unsigned short* __restrict__ probs) {
  __shared__ float red[4];
  __shared__ float red2[4];
  int m = blockIdx.x, t = threadIdx.x;
  int i = m & (SEQ - 1);
  const float scale = 0.04419417382415922f;   // 1/sqrt(512)
  const float NEG = -1e30f;
  float v0 = (t       <= i) ? logits[(size_t)m * SEQ + t      ] * scale : NEG;
  float v1 = (t + 256 <= i) ? logits[(size_t)m * SEQ + t + 256] * scale : NEG;
  float mx = fmaxf(v0, v1);
  #pragma unroll
  for (int off = 32; off; off >>= 1) mx = fmaxf(mx, __shfl_xor(mx, off));
  int w = t >> 6, lane = t & 63;
  if (lane == 0) red[w] = mx;
  __syncthreads();
  mx = fmaxf(fmaxf(red[0], red[1]), fmaxf(red[2], red[3]));
  float e0 = (t       <= i) ? __expf(v0 - mx) : 0.f;
  float e1 = (t + 256 <= i) ? __expf(v1 - mx) : 0.f;
  float s = e0 + e1;
  #pragma unroll
  for (int off = 32; off; off >>= 1) s += __shfl_xor(s, off);
  if (lane == 0) red2[w] = s;
  __syncthreads();
  s = red2[0] + red2[1] + red2[2] + red2[3];
  float inv = 1.f / s;
  probs[(size_t)m * SEQ + t]       = f2bf(e0 * inv);
  probs[(size_t)m * SEQ + t + 256] = f2bf(e1 * inv);
}

// ---------------------------------------------------------------------------
extern "C" void kernel_launch(void* const* d_in, const int* in_sizes, int n_in,
                              void* d_out, int out_size, void* d_ws, size_t ws_size,
                              hipStream_t stream) {
  (void)in_sizes; (void)n_in; (void)out_size; (void)ws_size;
  const float* q  = (const float*)d_in[0];
  const float* k  = (const float*)d_in[1];
  const float* v  = (const float*)d_in[2];
  const float* Wq = (const float*)d_in[3];
  const float* Wk = (const float*)d_in[4];
  const float* Wv = (const float*)d_in[5];
  float* out = (float*)d_out;

  char* ws = (char*)d_ws;
  size_t off = 0;
  auto alloc = [&](size_t bytes) -> void* {
    void* p = ws + off; off += (bytes + 255) & ~(size_t)255; return p;
  };
  float*          qpf    = (float*)         alloc((size_t)SEQ * DM * 4);
  unsigned short* kbf    = (unsigned short*)alloc((size_t)SEQ * DM * 2);
  unsigned short* vT     = (unsigned short*)alloc((size_t)DM * SEQ * 2);
  float*          af     = (float*)         alloc((size_t)NH * SEQ * DM * 4); // 4 MB
  float*          logits = (float*)         alloc((size_t)NH * SEQ * SEQ * 4);
  unsigned short* probs  = (unsigned short*)alloc((size_t)NH * SEQ * SEQ * 2);
  unsigned short* wbf    = (unsigned short*)alloc((size_t)NH * SEQ * DM * 2);

  hipMemsetAsync(af, 0, (size_t)NH * SEQ * DM * 4, stream);
  hipMemsetAsync(out, 0, (size_t)SEQ * DM * 4, stream);

  k0_convert<<<64, 256, 0, stream>>>(k, v, kbf, vT);
  k1_qproj<<<SEQ, 256, 0, stream>>>(q, Wq, qpf);
  // a[n,i,k]: per-j GEMM + f32 row-scale epilogue (17.2 GFLOP)
  ka3<<<512, 256, 0, stream>>>(Wk, qpf, af);
  // logits = a @ kbf^T : M=4096, N=512, K=256
  gemm_small<1,0><<<512, 256, 0, stream>>>((const void*)af, kbf, (void*)logits, NH*SEQ, SEQ, DM, 64);
  k4b_softmax<<<NH*SEQ, 256, 0, stream>>>(logits, probs);
  // w = probs @ v : M=4096, N=256, K=512 (B = vT)
  gemm_small<0,1><<<256, 256, 0, stream>>>((const void*)probs, vT, (void*)wbf, NH*SEQ, DM, SEQ, 64);
  // out: per-j GEMM + dot-vs-w epilogue (17.2 GFLOP)
  ko3<<<1024, 256, 0, stream>>>(Wv, qpf, wbf, out);
}

// Round 6
// 323.210 us; speedup vs baseline: 1.3309x; 1.3309x over previous
//
#include <hip/hip_runtime.h>
#include <hip/hip_bf16.h>
#include <math.h>

#define SEQ 512
#define DM  256
#define NH  8

typedef __attribute__((ext_vector_type(4))) float  f32x4;
typedef __attribute__((ext_vector_type(8))) __bf16 bf16x8;
typedef __attribute__((ext_vector_type(8))) short  s16x8;

__device__ __forceinline__ short fb(float x) {
  __bf16 h = (__bf16)x;
  return __builtin_bit_cast(short, h);
}
__device__ __forceinline__ unsigned short f2bf(float f) {
  unsigned int u = __builtin_bit_cast(unsigned int, f);
  u += 0x7fffu + ((u >> 16) & 1u);
  return (unsigned short)(u >> 16);
}
__device__ __forceinline__ float bf2f(unsigned short h) {
  unsigned int u = ((unsigned int)h) << 16;
  return __builtin_bit_cast(float, u);
}
__device__ __forceinline__ s16x8 cvt8(float4 a, float4 b) {
  s16x8 o;
  o[0]=fb(a.x); o[1]=fb(a.y); o[2]=fb(a.z); o[3]=fb(a.w);
  o[4]=fb(b.x); o[5]=fb(b.y); o[6]=fb(b.z); o[7]=fb(b.w);
  return o;
}
// async global->LDS, 16B/lane; dest is wave-uniform base (+lane*16 by HW)
__device__ __forceinline__ void gll16(const void* g, void* ldsbase) {
  __builtin_amdgcn_global_load_lds((const __attribute__((address_space(1))) void*)g,
                                   (__attribute__((address_space(3))) void*)ldsbase,
                                   16, 0, 0);
}

// ---------------------------------------------------------------------------
// kconv: f32 -> bf16 streaming convert (grid*256*32 elements)
__global__ __launch_bounds__(256) void kconv(const float* __restrict__ src,
                                             unsigned short* __restrict__ dst) {
  size_t base = ((size_t)blockIdx.x * 256 + threadIdx.x) * 32;
  #pragma unroll
  for (int u = 0; u < 4; u++) {
    float4 a = *(const float4*)(src + base + u * 8);
    float4 b = *(const float4*)(src + base + u * 8 + 4);
    *(s16x8*)(dst + base + u * 8) = cvt8(a, b);
  }
}

// ---------------------------------------------------------------------------
// K0: blocks 0..31 convert k (f32->bf16); blocks 32..63 transpose v -> vT bf16
__global__ __launch_bounds__(256) void k0_convert(const float* __restrict__ kin,
                                                  const float* __restrict__ vin,
                                                  unsigned short* __restrict__ kbf,
                                                  unsigned short* __restrict__ vT) {
  __shared__ unsigned short tl[64][72];
  int b = blockIdx.x, t = threadIdx.x;
  if (b < 32) {
    int base = b * 4096 + t * 16;
    float4 a0 = *(const float4*)(kin + base);
    float4 a1 = *(const float4*)(kin + base + 4);
    float4 a2 = *(const float4*)(kin + base + 8);
    float4 a3 = *(const float4*)(kin + base + 12);
    *(s16x8*)(kbf + base)     = cvt8(a0, a1);
    *(s16x8*)(kbf + base + 8) = cvt8(a2, a3);
  } else {
    int tb = b - 32;
    int i0 = (tb >> 2) * 64;
    int m0 = (tb & 3) * 64;
    int r = t >> 2, cq = t & 3;
    #pragma unroll
    for (int u = 0; u < 4; u++) {
      float4 x = *(const float4*)(vin + (size_t)(i0 + r) * DM + m0 + cq * 16 + u * 4);
      tl[cq*16 + u*4 + 0][r] = (unsigned short)fb(x.x);
      tl[cq*16 + u*4 + 1][r] = (unsigned short)fb(x.y);
      tl[cq*16 + u*4 + 2][r] = (unsigned short)fb(x.z);
      tl[cq*16 + u*4 + 3][r] = (unsigned short)fb(x.w);
    }
    __syncthreads();
    int mm = t >> 2;
    s16x8 w0, w1;
    #pragma unroll
    for (int e = 0; e < 8; e++) { w0[e] = tl[mm][cq*16 + e]; w1[e] = tl[mm][cq*16 + 8 + e]; }
    *(s16x8*)(vT + (size_t)(m0 + mm) * SEQ + i0 + cq * 16)     = w0;
    *(s16x8*)(vT + (size_t)(m0 + mm) * SEQ + i0 + cq * 16 + 8) = w1;
  }
}

// ---------------------------------------------------------------------------
// K1: qp = q @ Wq^T  (f32 + bf16 outputs)
__global__ __launch_bounds__(256) void k1_qproj(const float* __restrict__ q,
                                                const float* __restrict__ Wq,
                                                float* __restrict__ qpf,
                                                unsigned short* __restrict__ qpb) {
  __shared__ __align__(16) float qrow[DM];
  int i = blockIdx.x, t = threadIdx.x;
  if (t < 64) *(float4*)&qrow[t*4] = *(const float4*)(q + (size_t)i * DM + t * 4);
  __syncthreads();
  int w = t >> 6, lane = t & 63;
  for (int jj = 0; jj < 64; jj++) {
    int j = w * 64 + jj;
    float4 wv = *(const float4*)(Wq + (size_t)j * DM + lane * 4);
    float s = wv.x*qrow[lane*4] + wv.y*qrow[lane*4+1] + wv.z*qrow[lane*4+2] + wv.w*qrow[lane*4+3];
    #pragma unroll
    for (int off = 32; off; off >>= 1) s += __shfl_xor(s, off);
    if (lane == 0) { qpf[(size_t)i*DM + j] = s; qpb[(size_t)i*DM + j] = f2bf(s); }
  }
}

// ---------------------------------------------------------------------------
// ka4: a-partials. Per block (head, jsplit, itile): for 4 j's, GEMM
// [qp*scal](64 x 256bf16-K) @ Wkb_j^T -> accumulate acc(64 x 256) over j,kt.
// A reg-staged with row-scale qp[i,j]; B via global_load_lds (swizzle pair).
// Output: disjoint store into af8[jsplit] (no atomics). grid 512, 256 thr.
__global__ __launch_bounds__(256) void ka4(const unsigned short* __restrict__ Wkb,
                                           const float* __restrict__ qpf,
                                           float* __restrict__ af8) {
  __shared__ __align__(16) unsigned short lA[64 * 72];
  __shared__ __align__(16) unsigned short lB[256 * 64];   // linear (gll16)
  int bid = blockIdx.x;
  int head = bid & 7, rest = bid >> 3;
  int jsplit = rest >> 3, itile = rest & 7;
  int m0 = itile * 64;
  int t = threadIdx.x, w = t >> 6, lane = t & 63;
  int r = lane & 15, hi = lane >> 4;
  int srow = t >> 2, sc16 = (t & 3) * 16;

  f32x4 acc[4][4] = {};
  for (int jj = 0; jj < 4; jj++) {
    int jcol = head*32 + jsplit*4 + jj;
    const unsigned short* Bj = Wkb + (size_t)jcol * 65536;
    for (int kt = 0; kt < 4; kt++) {
      __syncthreads();                         // prior reads of lA/lB done
      #pragma unroll
      for (int it = 0; it < 8; it++) {         // lB: 256x64 bf16, 32 KB
        int chunk = w * 8 + it;                // 1 KB per gll16 wave-op
        int row = chunk * 8 + (lane >> 3);
        int cb = ((lane & 7) * 16) ^ ((row & 7) << 4);   // inverse-swz source
        gll16((const char*)(Bj + (size_t)row * 256 + kt * 64) + cb,
              (char*)lB + chunk * 1024);
      }
      { // lA: 64x64, qp row-scaled by qp[i,jcol], f32->bf16, pad-72
        float scal = qpf[(size_t)(m0 + srow) * DM + jcol];
        const float* src = qpf + (size_t)(m0 + srow) * DM + kt * 64 + sc16;
        float4 x0 = *(const float4*)src,     x1 = *(const float4*)(src + 4);
        float4 x2 = *(const float4*)(src + 8), x3 = *(const float4*)(src + 12);
        x0.x*=scal; x0.y*=scal; x0.z*=scal; x0.w*=scal;
        x1.x*=scal; x1.y*=scal; x1.z*=scal; x1.w*=scal;
        x2.x*=scal; x2.y*=scal; x2.z*=scal; x2.w*=scal;
        x3.x*=scal; x3.y*=scal; x3.z*=scal; x3.w*=scal;
        *(s16x8*)&lA[srow*72 + sc16]     = cvt8(x0, x1);
        *(s16x8*)&lA[srow*72 + sc16 + 8] = cvt8(x2, x3);
      }
      __syncthreads();                         // drains vmcnt+lgkm (compiler)
      #pragma unroll
      for (int kk = 0; kk < 2; kk++) {
        int kc = kk*32 + hi*8;
        bf16x8 afr[4], bfr[4];
        #pragma unroll
        for (int mf = 0; mf < 4; mf++)
          afr[mf] = *(const bf16x8*)&lA[(mf*16 + r)*72 + kc];
        #pragma unroll
        for (int nf = 0; nf < 4; nf++) {
          int bn = w*64 + nf*16 + r;
          bfr[nf] = *(const bf16x8*)((const char*)lB + bn*128 + ((kc*2) ^ ((bn&7)<<4)));
        }
        #pragma unroll
        for (int mf = 0; mf < 4; mf++)
          #pragma unroll
          for (int nf = 0; nf < 4; nf++)
            acc[mf][nf] = __builtin_amdgcn_mfma_f32_16x16x32_bf16(afr[mf], bfr[nf], acc[mf][nf], 0, 0, 0);
      }
    }
  }
  float* dst = af8 + (size_t)jsplit * (NH * SEQ * DM);
  #pragma unroll
  for (int mf = 0; mf < 4; mf++)
    #pragma unroll
    for (int nf = 0; nf < 4; nf++)
      #pragma unroll
      for (int qq = 0; qq < 4; qq++) {
        int row = m0 + mf*16 + hi*4 + qq;
        int col = w*64 + nf*16 + r;
        dst[((size_t)head * SEQ + row) * DM + col] = acc[mf][nf][qq];
      }
}

// ---------------------------------------------------------------------------
// kfold: abf[x] = bf16( sum_{s<8} af8[s][x] ), x over 8*512*256
__global__ __launch_bounds__(256) void kfold(const float* __restrict__ af8,
                                             unsigned short* __restrict__ abf) {
  const size_t S = (size_t)NH * SEQ * DM;
  size_t idx = ((size_t)blockIdx.x * 256 + threadIdx.x) * 8;
  float4 s0 = {0,0,0,0}, s1 = {0,0,0,0};
  #pragma unroll
  for (int p = 0; p < 8; p++) {
    float4 a = *(const float4*)(af8 + p * S + idx);
    float4 b = *(const float4*)(af8 + p * S + idx + 4);
    s0.x+=a.x; s0.y+=a.y; s0.z+=a.z; s0.w+=a.w;
    s1.x+=b.x; s1.y+=b.y; s1.z+=b.z; s1.w+=b.w;
  }
  *(s16x8*)(abf + idx) = cvt8(s0, s1);
}

// ---------------------------------------------------------------------------
// ko4: out. Per block (head, jsplit, itile): for 4 j's, GEMM
// qp(64 x K) @ Wvb_j^T -> tmp(64 x 256), then out[i,jcol] = sum_b tmp*w.
// A and B both via global_load_lds (swizzle pair); w staged once in LDS.
// grid 512, 256 thr, ~74 KiB LDS.
__global__ __launch_bounds__(256) void ko4(const unsigned short* __restrict__ Wvb,
                                           const unsigned short* __restrict__ qpb,
                                           const unsigned short* __restrict__ wbf,
                                           float* __restrict__ out) {
  __shared__ __align__(16) unsigned short lA[64 * 64];    // linear (gll16)
  __shared__ __align__(16) unsigned short lB[256 * 64];   // linear (gll16)
  __shared__ __align__(16) unsigned short lw[64 * 264];
  int bid = blockIdx.x;
  int head = bid & 7, rest = bid >> 3;
  int jsplit = rest >> 3, itile = rest & 7;
  int m0 = itile * 64;
  int t = threadIdx.x, w = t >> 6, lane = t & 63;
  int r = lane & 15, hi = lane >> 4;

  { // stage lw: w[head, m0..+64, 0..256] bf16
    int row = t >> 2, c64 = (t & 3) * 64;
    const unsigned short* sw = wbf + ((size_t)head * SEQ + m0 + row) * DM + c64;
    #pragma unroll
    for (int u = 0; u < 8; u++)
      *(s16x8*)&lw[row*264 + c64 + u*8] = *(const s16x8*)(sw + u*8);
  }

  for (int jj = 0; jj < 4; jj++) {
    int jcol = head*32 + jsplit*4 + jj;
    const unsigned short* Bj = Wvb + (size_t)jcol * 65536;
    f32x4 tmp[4][4] = {};
    for (int kt = 0; kt < 4; kt++) {
      __syncthreads();
      #pragma unroll
      for (int it = 0; it < 2; it++) {         // lA: 64x64 from qpb, 8 KB
        int chunk = w * 2 + it;
        int row = chunk * 8 + (lane >> 3);
        int cb = ((lane & 7) * 16) ^ ((row & 7) << 4);
        gll16((const char*)(qpb + (size_t)(m0 + row) * 256 + kt * 64) + cb,
              (char*)lA + chunk * 1024);
      }
      #pragma unroll
      for (int it = 0; it < 8; it++) {         // lB: 256x64 from Wvb, 32 KB
        int chunk = w * 8 + it;
        int row = chunk * 8 + (lane >> 3);
        int cb = ((lane & 7) * 16) ^ ((row & 7) << 4);
        gll16((const char*)(Bj + (size_t)row * 256 + kt * 64) + cb,
              (char*)lB + chunk * 1024);
      }
      __syncthreads();
      #pragma unroll
      for (int kk = 0; kk < 2; kk++) {
        int kc = kk*32 + hi*8;
        bf16x8 afr[4], bfr[4];
        #pragma unroll
        for (int mf = 0; mf < 4; mf++) {
          int row = mf*16 + r;
          afr[mf] = *(const bf16x8*)((const char*)lA + row*128 + ((kc*2) ^ ((row&7)<<4)));
        }
        #pragma unroll
        for (int nf = 0; nf < 4; nf++) {
          int bn = w*64 + nf*16 + r;
          bfr[nf] = *(const bf16x8*)((const char*)lB + bn*128 + ((kc*2) ^ ((bn&7)<<4)));
        }
        #pragma unroll
        for (int mf = 0; mf < 4; mf++)
          #pragma unroll
          for (int nf = 0; nf < 4; nf++)
            tmp[mf][nf] = __builtin_amdgcn_mfma_f32_16x16x32_bf16(afr[mf], bfr[nf], tmp[mf][nf], 0, 0, 0);
      }
    }
    // epilogue: out[i,jcol] += sum over this wave's 64 b-cols; reduce over r
    #pragma unroll
    for (int mf = 0; mf < 4; mf++)
      #pragma unroll
      for (int qq = 0; qq < 4; qq++) {
        int rloc = mf*16 + hi*4 + qq;
        float pp = 0.f;
        #pragma unroll
        for (int nf = 0; nf < 4; nf++)
          pp += tmp[mf][nf][qq] * bf2f(lw[rloc*264 + w*64 + nf*16 + r]);
        pp += __shfl_xor(pp, 1);
        pp += __shfl_xor(pp, 2);
        pp += __shfl_xor(pp, 4);
        pp += __shfl_xor(pp, 8);
        if (r == 0) atomicAdd(&out[(size_t)(m0 + rloc) * DM + jcol], pp);
      }
  }
}

// ---------------------------------------------------------------------------
// Small 64x64-tile NT GEMM: C[M,N] = A[M,K] * B[N,K]^T, 4 waves (2x2)
template<int CONVA, int OUTBF>
__global__ __launch_bounds__(256) void gemm_small(const void* __restrict__ Ap,
                                                  const unsigned short* __restrict__ B,
                                                  void* __restrict__ Cp,
                                                  int M, int N, int K, int nMtiles) {
  __shared__ __align__(16) unsigned short lA[64 * 72];
  __shared__ __align__(16) unsigned short lB[64 * 72];
  int bid = blockIdx.x;
  int mtile = bid % nMtiles, ntile = bid / nMtiles;
  int m0 = mtile * 64, n0 = ntile * 64;
  int t = threadIdx.x, w = t >> 6, lane = t & 63;
  int wr = w >> 1, wcc = w & 1;
  f32x4 acc[2][2] = {};
  for (int kt = 0; kt < K; kt += 64) {
    __syncthreads();
    #pragma unroll
    for (int rep = 0; rep < 2; rep++) {
      int sc = rep * 256 + t;
      int row = sc >> 3, c8 = sc & 7;
      if (CONVA) {
        const float* src = (const float*)Ap + (size_t)(m0 + row) * K + kt + c8 * 8;
        float4 u0 = *(const float4*)src, u1 = *(const float4*)(src + 4);
        *(s16x8*)&lA[row * 72 + c8 * 8] = cvt8(u0, u1);
      } else {
        *(s16x8*)&lA[row * 72 + c8 * 8] =
            *(const s16x8*)((const unsigned short*)Ap + (size_t)(m0 + row) * K + kt + c8 * 8);
      }
      *(s16x8*)&lB[row * 72 + c8 * 8] = *(const s16x8*)(B + (size_t)(n0 + row) * K + kt + c8 * 8);
    }
    __syncthreads();
    #pragma unroll
    for (int kk = 0; kk < 2; kk++) {
      int r = lane & 15, kc = kk * 32 + (lane >> 4) * 8;
      bf16x8 afr[2], bfr[2];
      #pragma unroll
      for (int mf = 0; mf < 2; mf++) afr[mf] = *(const bf16x8*)&lA[(wr*32 + mf*16 + r) * 72 + kc];
      #pragma unroll
      for (int nf = 0; nf < 2; nf++) bfr[nf] = *(const bf16x8*)&lB[(wcc*32 + nf*16 + r) * 72 + kc];
      #pragma unroll
      for (int mf = 0; mf < 2; mf++)
        #pragma unroll
        for (int nf = 0; nf < 2; nf++)
          acc[mf][nf] = __builtin_amdgcn_mfma_f32_16x16x32_bf16(afr[mf], bfr[nf], acc[mf][nf], 0, 0, 0);
    }
  }
  int cr = (lane >> 4) * 4, cc = lane & 15;
  #pragma unroll
  for (int mf = 0; mf < 2; mf++)
    #pragma unroll
    for (int nf = 0; nf < 2; nf++)
      #pragma unroll
      for (int qq = 0; qq < 4; qq++) {
        int row = m0 + wr*32 + mf*16 + cr + qq;
        int col = n0 + wcc*32 + nf*16 + cc;
        float vv = acc[mf][nf][qq];
        if (OUTBF) ((unsigned short*)Cp)[(size_t)row * N + col] = f2bf(vv);
        else       ((float*)Cp)[(size_t)row * N + col] = vv;
      }
}

// ---------------------------------------------------------------------------
// softmax over rows of logits[n*512+i][l], causal l<=i, scale 1/sqrt(512)
__global__ __launch_bounds__(256) void k4b_softmax(const float* __restrict__ logits,
                                                   unsigned short* __restrict__ probs) {
  __shared__ float red[4];
  __shared__ float red2[4];
  int m = blockIdx.x, t = threadIdx.x;
  int i = m & (SEQ - 1);
  const float scale = 0.04419417382415922f;   // 1/sqrt(512)
  const float NEG = -1e30f;
  float v0 = (t       <= i) ? logits[(size_t)m * SEQ + t      ] * scale : NEG;
  float v1 = (t + 256 <= i) ? logits[(size_t)m * SEQ + t + 256] * scale : NEG;
  float mx = fmaxf(v0, v1);
  #pragma unroll
  for (int off = 32; off; off >>= 1) mx = fmaxf(mx, __shfl_xor(mx, off));
  int w = t >> 6, lane = t & 63;
  if (lane == 0) red[w] = mx;
  __syncthreads();
  mx = fmaxf(fmaxf(red[0], red[1]), fmaxf(red[2], red[3]));
  float e0 = (t       <= i) ? __expf(v0 - mx) : 0.f;
  float e1 = (t + 256 <= i) ? __expf(v1 - mx) : 0.f;
  float s = e0 + e1;
  #pragma unroll
  for (int off = 32; off; off >>= 1) s += __shfl_xor(s, off);
  if (lane == 0) red2[w] = s;
  __syncthreads();
  s = red2[0] + red2[1] + red2[2] + red2[3];
  float inv = 1.f / s;
  probs[(size_t)m * SEQ + t]       = f2bf(e0 * inv);
  probs[(size_t)m * SEQ + t + 256] = f2bf(e1 * inv);
}

// ---------------------------------------------------------------------------
extern "C" void kernel_launch(void* const* d_in, const int* in_sizes, int n_in,
                              void* d_out, int out_size, void* d_ws, size_t ws_size,
                              hipStream_t stream) {
  (void)in_sizes; (void)n_in; (void)out_size; (void)ws_size;
  const float* q  = (const float*)d_in[0];
  const float* k  = (const float*)d_in[1];
  const float* v  = (const float*)d_in[2];
  const float* Wq = (const float*)d_in[3];
  const float* Wk = (const float*)d_in[4];
  const float* Wv = (const float*)d_in[5];
  float* out = (float*)d_out;

  char* ws = (char*)d_ws;
  size_t off = 0;
  auto alloc = [&](size_t bytes) -> void* {
    void* p = ws + off; off += (bytes + 255) & ~(size_t)255; return p;
  };
  float*          qpf    = (float*)         alloc((size_t)SEQ * DM * 4);
  unsigned short* qpb    = (unsigned short*)alloc((size_t)SEQ * DM * 2);
  unsigned short* kbf    = (unsigned short*)alloc((size_t)SEQ * DM * 2);
  unsigned short* vT     = (unsigned short*)alloc((size_t)DM * SEQ * 2);
  unsigned short* Wkb    = (unsigned short*)alloc((size_t)DM * DM * DM * 2);  // 32 MB
  unsigned short* Wvb    = (unsigned short*)alloc((size_t)DM * DM * DM * 2);  // 32 MB
  float*          af8    = (float*)         alloc((size_t)8 * NH * SEQ * DM * 4); // 32 MB
  unsigned short* abf    = (unsigned short*)alloc((size_t)NH * SEQ * DM * 2); // 2 MB
  float*          logits = (float*)         alloc((size_t)NH * SEQ * SEQ * 4);
  unsigned short* probs  = (unsigned short*)alloc((size_t)NH * SEQ * SEQ * 2);
  unsigned short* wbf    = (unsigned short*)alloc((size_t)NH * SEQ * DM * 2);

  hipMemsetAsync(out, 0, (size_t)SEQ * DM * 4, stream);

  kconv<<<2048, 256, 0, stream>>>(Wk, Wkb);
  kconv<<<2048, 256, 0, stream>>>(Wv, Wvb);
  k0_convert<<<64, 256, 0, stream>>>(k, v, kbf, vT);
  k1_qproj<<<SEQ, 256, 0, stream>>>(q, Wq, qpf, qpb);
  // a-partials: per-j GEMM, A row-scaled; disjoint stores (17.2 GFLOP)
  ka4<<<512, 256, 0, stream>>>(Wkb, qpf, af8);
  kfold<<<512, 256, 0, stream>>>(af8, abf);
  // logits = a @ kbf^T : M=4096, N=512, K=256
  gemm_small<0,0><<<512, 256, 0, stream>>>((const void*)abf, kbf, (void*)logits, NH*SEQ, SEQ, DM, 64);
  k4b_softmax<<<NH*SEQ, 256, 0, stream>>>(logits, probs);
  // w = probs @ v : M=4096, N=256, K=512 (B = vT)
  gemm_small<0,1><<<256, 256, 0, stream>>>((const void*)probs, vT, (void*)wbf, NH*SEQ, DM, SEQ, 64);
  // out: per-j GEMM + dot-vs-w epilogue (17.2 GFLOP)
  ko4<<<512, 256, 0, stream>>>(Wvb, qpb, wbf, out);
}